// Round 6
// baseline (956.747 us; speedup 1.0000x reference)
//
#include <hip/hip_runtime.h>

#define NITER 10
#define PAD 32      // CSR segment padding = pipeline chunk size
#define NBLK 250    // main-kernel blocks (250*8 waves = 2000 nodes exactly)
#define MAIN_T 512  // 8 waves per block
#define CAP 160     // per-wave LDS edge capacity (max padded degree ~128)

// ---------------- helpers ----------------

__device__ __forceinline__ float bf2f_lo(uint32_t v) { return __uint_as_float(v << 16); }
__device__ __forceinline__ float bf2f_hi(uint32_t v) { return __uint_as_float(v & 0xFFFF0000u); }

__device__ __forceinline__ uint32_t f2bf_bits(float f) {  // RNE, top 16 bits
  uint32_t b = __float_as_uint(f);
  b += 0x7FFFu + ((b >> 16) & 1u);
  return b >> 16;
}
__device__ __forceinline__ uint32_t pack_bf16x2(float lo, float hi) {
  return f2bf_bits(lo) | (f2bf_bits(hi) << 16);
}

// ---------------- setup kernel 1: partial histograms + edge-array zeroing ----------------

__global__ __launch_bounds__(1024) void hist_zero_kernel(
    const int* __restrict__ src, const int* __restrict__ tgt,
    int* __restrict__ partS, int* __restrict__ partT,
    uint32_t* __restrict__ edges, int E, int N, int zwords) {
  if (blockIdx.x < 8) {
    __shared__ int h[4096];
    for (int i = threadIdx.x; i < 2 * N; i += 1024) h[i] = 0;
    __syncthreads();
    const int chunk = E / 8;
    const int base = blockIdx.x * chunk;
    for (int k = threadIdx.x; k < chunk; k += 1024) {
      int e = base + k;
      atomicAdd(&h[src[e]], 1);
      atomicAdd(&h[N + tgt[e]], 1);
    }
    __syncthreads();
    for (int i = threadIdx.x; i < N; i += 1024) {
      partS[blockIdx.x * 2048 + i] = h[i];
      partT[blockIdx.x * 2048 + i] = h[N + i];
    }
  } else {
    int tid = (blockIdx.x - 8) * 1024 + threadIdx.x;
    for (int i = tid; i < zwords; i += 24 * 1024) edges[i] = 0u;
  }
}

// ---------------- setup kernel 2: padded exclusive scan (+ zero barrier counters) ----------

__global__ void scan_pad_kernel(const int* __restrict__ partS, const int* __restrict__ partT,
                                int* __restrict__ offS, int* __restrict__ offT,
                                int* __restrict__ curS, int* __restrict__ curT,
                                uint32_t* __restrict__ bar, int N) {
  if (blockIdx.x == 0 && threadIdx.x < 192) bar[threadIdx.x] = 0u;  // barrier ctrs + gen
  const int* part = (blockIdx.x == 0) ? partS : partT;
  int* off = (blockIdx.x == 0) ? offS : offT;
  int* cur = (blockIdx.x == 0) ? curS : curT;
  __shared__ int tsum[256];
  int tid = threadIdx.x;
  int base = tid * 8;
  int v[8];
  int s = 0;
#pragma unroll
  for (int i = 0; i < 8; ++i) {
    int idx = base + i;
    int c = 0;
    if (idx < N) {
#pragma unroll
      for (int k = 0; k < 8; ++k) c += part[k * 2048 + idx];
      c = (c + (PAD - 1)) & ~(PAD - 1);
    }
    v[i] = s;
    s += c;
  }
  tsum[tid] = s;
  __syncthreads();
  for (int d = 1; d < 256; d <<= 1) {
    int t = (tid >= d) ? tsum[tid - d] : 0;
    __syncthreads();
    tsum[tid] += t;
    __syncthreads();
  }
  int tbase = tsum[tid] - s;
#pragma unroll
  for (int i = 0; i < 8; ++i) {
    int idx = base + i;
    if (idx < N) {
      int o = tbase + v[i];
      off[idx] = o;
      cur[idx] = o;
    } else if (idx == N) {
      off[idx] = tbase + v[i];
    }
  }
}

// ---------------- setup kernel 3: scatter edges into CSR ----------------

__global__ void scatter_kernel(const int* __restrict__ src, const int* __restrict__ tgt,
                               const float* __restrict__ w,
                               int* __restrict__ curS, int* __restrict__ curT,
                               uint32_t* __restrict__ edgeS, uint32_t* __restrict__ edgeT, int E) {
  int e = blockIdx.x * blockDim.x + threadIdx.x;
  if (e < E) {
    int s = src[e], t = tgt[e];
    uint32_t wb = __float_as_uint(w[e]);
    wb = (wb + 0x7FFFu + ((wb >> 16) & 1u)) & 0xFFFF0000u;
    int p = atomicAdd(&curS[s], 1);
    edgeS[p] = (uint32_t)t | wb;  // mu pass: grouped by src, gathers fx[tgt]
    int q = atomicAdd(&curT[t], 1);
    edgeT[q] = (uint32_t)s | wb;  // agg pass: grouped by tgt, gathers err[src]
  }
}

// ---------------- main cooperative kernel ----------------

// Tree barrier (round-4 proven): vmcnt(0) drains sc1 write-through stores to LLC before
// arrival; all cross-block message reads are sc1 (LLC) loads, so NO cache invalidation
// is needed (round 5's buffer_inv was a 3.3x regression).
__device__ __forceinline__ void gbar(uint32_t* bar, uint32_t target) {
  asm volatile("s_waitcnt vmcnt(0)" ::: "memory");
  __syncthreads();
  if (threadIdx.x == 0) {
    uint32_t* leaf = bar + (blockIdx.x & 7) * 16;
    uint32_t* root = bar + 128;
    uint32_t* gen = bar + 144;
    const uint32_t leafsz = ((blockIdx.x & 7) < 2) ? 32u : 31u;  // 250 = 2*32 + 6*31
    uint32_t lo = __hip_atomic_fetch_add(leaf, 1u, __ATOMIC_RELAXED, __HIP_MEMORY_SCOPE_AGENT);
    if (lo == leafsz - 1) {
      __hip_atomic_store(leaf, 0u, __ATOMIC_RELAXED, __HIP_MEMORY_SCOPE_AGENT);
      uint32_t ro = __hip_atomic_fetch_add(root, 1u, __ATOMIC_RELAXED, __HIP_MEMORY_SCOPE_AGENT);
      if (ro == 7u) {
        __hip_atomic_store(root, 0u, __ATOMIC_RELAXED, __HIP_MEMORY_SCOPE_AGENT);
        __hip_atomic_store(gen, target, __ATOMIC_RELAXED, __HIP_MEMORY_SCOPE_AGENT);
      }
    }
    while (__hip_atomic_load(gen, __ATOMIC_RELAXED, __HIP_MEMORY_SCOPE_AGENT) < target)
      __builtin_amdgcn_s_sleep(1);
  }
  __syncthreads();
  asm volatile("" ::: "memory");  // compiler fence only
}

// ---- pipelined CSR gather: chunks of 32, ping-pong register buffers ----
// issue32: read 32 edge words (LDS, wave-uniform -> broadcast) and launch 32 LLC loads.
// consume32: unpack w, 64 FMAs. All array indices compile-time constant (no scratch).

__device__ __forceinline__ void issue32(const uint32_t* __restrict__ se, int p,
                                        const uint32_t* buf, int lane,
                                        uint32_t (&e)[32], uint32_t (&v)[32]) {
#pragma unroll
  for (int j = 0; j < 32; ++j) e[j] = se[p + j];
#pragma unroll
  for (int j = 0; j < 32; ++j)
    v[j] = __hip_atomic_load(&buf[((e[j] & 0xFFFFu) << 6) + lane], __ATOMIC_RELAXED,
                             __HIP_MEMORY_SCOPE_AGENT);
}

__device__ __forceinline__ void consume32(const uint32_t (&e)[32], const uint32_t (&v)[32],
                                          float (&a0)[4], float (&a1)[4]) {
#pragma unroll
  for (int j = 0; j < 32; ++j) {
    float wj = __uint_as_float(e[j] & 0xFFFF0000u);
    a0[j & 3] = fmaf(wj, bf2f_lo(v[j]), a0[j & 3]);
    a1[j & 3] = fmaf(wj, bf2f_hi(v[j]), a1[j & 3]);
  }
}

__device__ __forceinline__ void gather_pipe(const uint32_t* __restrict__ se, int len,
                                            const uint32_t* buf, int lane,
                                            float& o0, float& o1) {
  float a0[4] = {0.f, 0.f, 0.f, 0.f}, a1[4] = {0.f, 0.f, 0.f, 0.f};
  if (len > 0) {
    uint32_t eA[32], vA[32], eB[32], vB[32];
    issue32(se, 0, buf, lane, eA, vA);
    bool inA = true;
    for (int p = 32; p < len; p += 32) {
      if (inA) {
        issue32(se, p, buf, lane, eB, vB);  // next chunk in flight
        consume32(eA, vA, a0, a1);          // while consuming current
      } else {
        issue32(se, p, buf, lane, eA, vA);
        consume32(eB, vB, a0, a1);
      }
      inA = !inA;
    }
    if (inA) consume32(eA, vA, a0, a1);
    else     consume32(eB, vB, a0, a1);
  }
  o0 = (a0[0] + a0[1]) + (a0[2] + a0[3]);
  o1 = (a1[0] + a1[1]) + (a1[2] + a1[3]);
}

__global__ __launch_bounds__(MAIN_T, 1) void pc_main(
    const float* __restrict__ x, float* __restrict__ out,
    const int* __restrict__ offS, const uint32_t* __restrict__ edS,
    const int* __restrict__ offT, const uint32_t* __restrict__ edT,
    uint32_t* fx32, uint32_t* err32, const float* __restrict__ mask,
    uint32_t* bar, int N) {
  const int wid = threadIdx.x >> 6;
  const int lane = threadIdx.x & 63;
  const int n = blockIdx.x * (MAIN_T / 64) + wid;  // 250*8 = 2000, always valid
  const int i = (n << 6) + lane;
  const float m = mask[n];
  const int s0 = offS[n], s1 = offS[n + 1];
  const int t0 = offT[n], t1 = offT[n + 1];
  const int lenS = s1 - s0, lenT = t1 - t0;

  // stage this wave's CSR slices into LDS once (wave-private)
  __shared__ uint32_t sE[2][MAIN_T / 64][CAP];
  const bool fitS = (lenS <= CAP), fitT = (lenT <= CAP);
  if (fitS)
    for (int k = lane; k < lenS; k += 64) sE[0][wid][k] = edS[s0 + k];
  if (fitT)
    for (int k = lane; k < lenT; k += 64) sE[1][wid][k] = edT[t0 + k];

  // transpose-in: lane l owns batch (2l, 2l+1) of node n; x stays in registers
  float x0 = x[(2 * lane) * N + n];
  float x1 = x[(2 * lane + 1) * N + n];
  float fx0 = tanhf(x0), fx1 = tanhf(x1);
  __hip_atomic_store(&fx32[i], pack_bf16x2(fx0, fx1), __ATOMIC_RELAXED, __HIP_MEMORY_SCOPE_AGENT);
  uint32_t gen = 0;
  gbar(bar, ++gen);

  for (int it = 0; it < NITER; ++it) {
    float mu0, mu1;
    if (fitS) gather_pipe(sE[0][wid], lenS, fx32, lane, mu0, mu1);
    else      gather_pipe(edS + s0, lenS, fx32, lane, mu0, mu1);
    const float e0 = (x0 - mu0) * m;
    const float e1 = (x1 - mu1) * m;
    __hip_atomic_store(&err32[i], pack_bf16x2(e0, e1), __ATOMIC_RELAXED, __HIP_MEMORY_SCOPE_AGENT);
    gbar(bar, ++gen);

    float a0, a1;
    if (fitT) gather_pipe(sE[1][wid], lenT, err32, lane, a0, a1);
    else      gather_pipe(edT + t0, lenT, err32, lane, a0, a1);
    const float dx0 = e0 - (1.f - fx0 * fx0) * a0;
    const float dx1 = e1 - (1.f - fx1 * fx1) * a1;
    x0 -= 0.5f * dx0 * m;
    x1 -= 0.5f * dx1 * m;
    fx0 = tanhf(x0);
    fx1 = tanhf(x1);
    if (it < NITER - 1) {
      __hip_atomic_store(&fx32[i], pack_bf16x2(fx0, fx1), __ATOMIC_RELAXED,
                         __HIP_MEMORY_SCOPE_AGENT);
      gbar(bar, ++gen);
    }
  }
  out[(2 * lane) * N + n] = x0;
  out[(2 * lane + 1) * N + n] = x1;
}

// ---------------- host ----------------

extern "C" void kernel_launch(void* const* d_in, const int* in_sizes, int n_in,
                              void* d_out, int out_size, void* d_ws, size_t ws_size,
                              hipStream_t stream) {
  const float* x = (const float*)d_in[0];
  const int* ei = (const int*)d_in[1];
  const float* w = (const float*)d_in[2];
  const float* mask = (const float*)d_in[3];
  const int E = in_sizes[2];  // 131072
  int N = in_sizes[3];        // 2000
  const int* src = ei;
  const int* tgt = ei + E;
  float* out = (float*)d_out;

  const int Epad = E + PAD * N;  // per-node pad-to-PAD headroom

  size_t off = 0;
  auto alloc = [&](size_t bytes) -> void* {
    off = (off + 255) & ~(size_t)255;
    void* p = (char*)d_ws + off;
    off += bytes;
    return p;
  };
  uint32_t* edgeS = (uint32_t*)alloc((size_t)Epad * 4);  // contiguous with edgeT: one zero pass
  uint32_t* edgeT = (uint32_t*)alloc((size_t)Epad * 4);
  int* partS = (int*)alloc(8 * 2048 * 4);
  int* partT = (int*)alloc(8 * 2048 * 4);
  int* offS = (int*)alloc(2048 * 4);
  int* offT = (int*)alloc(2048 * 4);
  int* curS = (int*)alloc(2048 * 4);
  int* curT = (int*)alloc(2048 * 4);
  uint32_t* fx32 = (uint32_t*)alloc((size_t)N * 64 * 4);
  uint32_t* err32 = (uint32_t*)alloc((size_t)N * 64 * 4);
  uint32_t* bar = (uint32_t*)alloc(256 * 4);

  hist_zero_kernel<<<32, 1024, 0, stream>>>(src, tgt, partS, partT, edgeS, E, N, 2 * Epad);
  scan_pad_kernel<<<2, 256, 0, stream>>>(partS, partT, offS, offT, curS, curT, bar, N);
  scatter_kernel<<<(E + 255) / 256, 256, 0, stream>>>(src, tgt, w, curS, curT, edgeS, edgeT, E);

  void* args[] = {(void*)&x,    (void*)&out,   (void*)&offS, (void*)&edgeS,
                  (void*)&offT, (void*)&edgeT, (void*)&fx32, (void*)&err32,
                  (void*)&mask, (void*)&bar,   (void*)&N};
  hipLaunchCooperativeKernel((const void*)pc_main, dim3(NBLK), dim3(MAIN_T), args, 0, stream);
}

// Round 7
// 429.705 us; speedup vs baseline: 2.2265x; 2.2265x over previous
//
#include <hip/hip_runtime.h>

#define NITER 10
#define PAD 8       // CSR segment padding / accumulator depth
#define NBLK 250    // main-kernel blocks (250*8 waves = 2000 nodes exactly)
#define MAIN_T 512  // 8 waves per block
#define CAP 160     // per-wave LDS edge capacity (max padded degree ~120)

// ---------------- helpers ----------------

__device__ __forceinline__ float bf2f_lo(uint32_t v) { return __uint_as_float(v << 16); }
__device__ __forceinline__ float bf2f_hi(uint32_t v) { return __uint_as_float(v & 0xFFFF0000u); }

__device__ __forceinline__ uint32_t f2bf_bits(float f) {  // RNE, top 16 bits
  uint32_t b = __float_as_uint(f);
  b += 0x7FFFu + ((b >> 16) & 1u);
  return b >> 16;
}
__device__ __forceinline__ uint32_t pack_bf16x2(float lo, float hi) {
  return f2bf_bits(lo) | (f2bf_bits(hi) << 16);
}

// ---------------- setup kernel 1: partial histograms + edge-array zeroing ----------------

__global__ __launch_bounds__(1024) void hist_zero_kernel(
    const int* __restrict__ src, const int* __restrict__ tgt,
    int* __restrict__ partS, int* __restrict__ partT,
    uint32_t* __restrict__ edges, int E, int N, int zwords) {
  if (blockIdx.x < 8) {
    __shared__ int h[4096];
    for (int i = threadIdx.x; i < 2 * N; i += 1024) h[i] = 0;
    __syncthreads();
    const int chunk = E / 8;
    const int base = blockIdx.x * chunk;
    for (int k = threadIdx.x; k < chunk; k += 1024) {
      int e = base + k;
      atomicAdd(&h[src[e]], 1);
      atomicAdd(&h[N + tgt[e]], 1);
    }
    __syncthreads();
    for (int i = threadIdx.x; i < N; i += 1024) {
      partS[blockIdx.x * 2048 + i] = h[i];
      partT[blockIdx.x * 2048 + i] = h[N + i];
    }
  } else {
    int tid = (blockIdx.x - 8) * 1024 + threadIdx.x;
    for (int i = tid; i < zwords; i += 24 * 1024) edges[i] = 0u;
  }
}

// ---------------- setup kernel 2: padded exclusive scan + true degrees + tag zeroing ------

__global__ void scan_pad_kernel(const int* __restrict__ partS, const int* __restrict__ partT,
                                int* __restrict__ offS, int* __restrict__ offT,
                                int* __restrict__ curS, int* __restrict__ curT,
                                int* __restrict__ degS, int* __restrict__ degT,
                                uint32_t* __restrict__ fxtag, uint32_t* __restrict__ errtag,
                                int N) {
  // zero generation tags (MUST happen every launch: harness does not re-poison d_ws)
  uint32_t* tags = (blockIdx.x == 0) ? fxtag : errtag;
  for (int i = threadIdx.x; i < 2048; i += 256) tags[i] = 0u;

  const int* part = (blockIdx.x == 0) ? partS : partT;
  int* off = (blockIdx.x == 0) ? offS : offT;
  int* cur = (blockIdx.x == 0) ? curS : curT;
  int* deg = (blockIdx.x == 0) ? degS : degT;
  __shared__ int tsum[256];
  int tid = threadIdx.x;
  int base = tid * 8;
  int v[8];
  int s = 0;
#pragma unroll
  for (int i = 0; i < 8; ++i) {
    int idx = base + i;
    int c = 0;
    if (idx < N) {
#pragma unroll
      for (int k = 0; k < 8; ++k) c += part[k * 2048 + idx];
      deg[idx] = c;                     // true degree (for tag checks)
      c = (c + (PAD - 1)) & ~(PAD - 1); // padded degree (for CSR layout)
    }
    v[i] = s;
    s += c;
  }
  tsum[tid] = s;
  __syncthreads();
  for (int d = 1; d < 256; d <<= 1) {
    int t = (tid >= d) ? tsum[tid - d] : 0;
    __syncthreads();
    tsum[tid] += t;
    __syncthreads();
  }
  int tbase = tsum[tid] - s;
#pragma unroll
  for (int i = 0; i < 8; ++i) {
    int idx = base + i;
    if (idx < N) {
      int o = tbase + v[i];
      off[idx] = o;
      cur[idx] = o;
    } else if (idx == N) {
      off[idx] = tbase + v[i];
    }
  }
}

// ---------------- setup kernel 3: scatter edges into CSR ----------------

__global__ void scatter_kernel(const int* __restrict__ src, const int* __restrict__ tgt,
                               const float* __restrict__ w,
                               int* __restrict__ curS, int* __restrict__ curT,
                               uint32_t* __restrict__ edgeS, uint32_t* __restrict__ edgeT, int E) {
  int e = blockIdx.x * blockDim.x + threadIdx.x;
  if (e < E) {
    int s = src[e], t = tgt[e];
    uint32_t wb = __float_as_uint(w[e]);
    wb = (wb + 0x7FFFu + ((wb >> 16) & 1u)) & 0xFFFF0000u;
    int p = atomicAdd(&curS[s], 1);
    edgeS[p] = (uint32_t)t | wb;  // mu pass: grouped by src, gathers fx[tgt]
    int q = atomicAdd(&curT[t], 1);
    edgeT[q] = (uint32_t)s | wb;  // agg pass: grouped by tgt, gathers err[src]
  }
}

// ---------------- main kernel: barrier-free dataflow ----------------
// Protocol: publish = {sc1 payload stores; s_waitcnt vmcnt(0); sc1 tag store}.
// Consume = {spin until all true-neighbor tags >= k; sc1 payload gathers}.
// Safety (no WAR overwrite) follows from edge duality: node c overwriting its
// err(k) with err(k+1) first requires fxtag[t] >= k+1 for ALL t with c->t, and
// t only publishes fx_v(k) after t finished gathering err(k) (which includes c).
// fx is parity double-buffered; err single-buffered. No global barriers at all.

template <typename EP>
__device__ __forceinline__ void wait_tags(EP se, int deg, int lane,
                                          const uint32_t* tags, uint32_t k) {
  for (;;) {
    bool ready = true;
    for (int j = lane; j < deg; j += 64) {
      uint32_t nb = se[j] & 0xFFFFu;
      ready &= (__hip_atomic_load(&tags[nb], __ATOMIC_RELAXED, __HIP_MEMORY_SCOPE_AGENT) >= k);
    }
    if (__all(ready)) break;
    __builtin_amdgcn_s_sleep(2);
  }
  asm volatile("" ::: "memory");  // no hoisting payload loads above the spin
}

template <typename EP>
__device__ __forceinline__ void gather8(EP se, int len, const uint32_t* buf, int lane,
                                        float& o0, float& o1) {
  float a0[PAD], a1[PAD];
#pragma unroll
  for (int j = 0; j < PAD; ++j) { a0[j] = 0.f; a1[j] = 0.f; }
  for (int p = 0; p < len; p += PAD) {
    uint32_t e[PAD];
#pragma unroll
    for (int j = 0; j < PAD; ++j) e[j] = se[p + j];
    uint32_t v[PAD];
#pragma unroll
    for (int j = 0; j < PAD; ++j)
      v[j] = __hip_atomic_load(&buf[((e[j] & 0xFFFFu) << 6) + lane], __ATOMIC_RELAXED,
                               __HIP_MEMORY_SCOPE_AGENT);
#pragma unroll
    for (int j = 0; j < PAD; ++j) {
      float wj = __uint_as_float(e[j] & 0xFFFF0000u);
      a0[j] = fmaf(wj, bf2f_lo(v[j]), a0[j]);
      a1[j] = fmaf(wj, bf2f_hi(v[j]), a1[j]);
    }
  }
  o0 = ((a0[0] + a0[1]) + (a0[2] + a0[3])) + ((a0[4] + a0[5]) + (a0[6] + a0[7]));
  o1 = ((a1[0] + a1[1]) + (a1[2] + a1[3])) + ((a1[4] + a1[5]) + (a1[6] + a1[7]));
}

__device__ __forceinline__ void publish(uint32_t* p, uint32_t val, uint32_t* tag, uint32_t k,
                                        int lane) {
  __hip_atomic_store(p, val, __ATOMIC_RELAXED, __HIP_MEMORY_SCOPE_AGENT);
  asm volatile("s_waitcnt vmcnt(0)" ::: "memory");  // payload at LLC before tag
  if (lane == 0) __hip_atomic_store(tag, k, __ATOMIC_RELAXED, __HIP_MEMORY_SCOPE_AGENT);
}

__global__ __launch_bounds__(MAIN_T, 2) void pc_main(
    const float* __restrict__ x, float* __restrict__ out,
    const int* __restrict__ offS, const int* __restrict__ degS, const uint32_t* __restrict__ edS,
    const int* __restrict__ offT, const int* __restrict__ degT, const uint32_t* __restrict__ edT,
    uint32_t* fx32, uint32_t* err32, uint32_t* fxtag, uint32_t* errtag,
    const float* __restrict__ mask, int N) {
  const int wid = threadIdx.x >> 6;
  const int lane = threadIdx.x & 63;
  const int n = blockIdx.x * (MAIN_T / 64) + wid;  // 250*8 = 2000, always valid
  const int i = (n << 6) + lane;
  const float m = mask[n];
  const int s0 = offS[n], s1 = offS[n + 1];
  const int t0 = offT[n], t1 = offT[n + 1];
  const int lenS = s1 - s0, lenT = t1 - t0;  // padded
  const int dS = degS[n], dT = degT[n];      // true

  // stage this wave's CSR slices into LDS once (wave-private, no syncs needed)
  __shared__ uint32_t sE[2][MAIN_T / 64][CAP];
  const bool fitS = (lenS <= CAP), fitT = (lenT <= CAP);
  if (fitS)
    for (int k = lane; k < lenS; k += 64) sE[0][wid][k] = edS[s0 + k];
  if (fitT)
    for (int k = lane; k < lenT; k += 64) sE[1][wid][k] = edT[t0 + k];

  // transpose-in: lane l owns batch (2l, 2l+1) of node n; x stays in registers
  float x0 = x[(2 * lane) * N + n];
  float x1 = x[(2 * lane + 1) * N + n];
  float fx0 = tanhf(x0), fx1 = tanhf(x1);
  publish(&fx32[i], pack_bf16x2(fx0, fx1), &fxtag[n], 1u, lane);  // fx_v(0) -> slot 0, tag 1

  for (uint32_t k = 1; k <= NITER; ++k) {
    // ---- phase 1: mu gather over fx_v(k-1), publish err(k) ----
    const uint32_t* fxbuf = fx32 + (size_t)((k - 1) & 1) * (N << 6);
    float mu0, mu1;
    if (fitS) {
      wait_tags(&sE[0][wid][0], dS, lane, fxtag, k);
      gather8(&sE[0][wid][0], lenS, fxbuf, lane, mu0, mu1);
    } else {
      wait_tags(edS + s0, dS, lane, fxtag, k);
      gather8(edS + s0, lenS, fxbuf, lane, mu0, mu1);
    }
    const float e0 = (x0 - mu0) * m;
    const float e1 = (x1 - mu1) * m;
    publish(&err32[i], pack_bf16x2(e0, e1), &errtag[n], k, lane);

    // ---- phase 2: agg gather over err(k), update x, publish fx_v(k) ----
    float a0, a1;
    if (fitT) {
      wait_tags(&sE[1][wid][0], dT, lane, errtag, k);
      gather8(&sE[1][wid][0], lenT, err32, lane, a0, a1);
    } else {
      wait_tags(edT + t0, dT, lane, errtag, k);
      gather8(edT + t0, lenT, err32, lane, a0, a1);
    }
    const float dx0 = e0 - (1.f - fx0 * fx0) * a0;
    const float dx1 = e1 - (1.f - fx1 * fx1) * a1;
    x0 -= 0.5f * dx0 * m;
    x1 -= 0.5f * dx1 * m;
    fx0 = tanhf(x0);
    fx1 = tanhf(x1);
    if (k < NITER)
      publish(&fx32[(size_t)(k & 1) * (N << 6) + i], pack_bf16x2(fx0, fx1), &fxtag[n], k + 1,
              lane);
  }
  out[(2 * lane) * N + n] = x0;
  out[(2 * lane + 1) * N + n] = x1;
}

// ---------------- host ----------------

extern "C" void kernel_launch(void* const* d_in, const int* in_sizes, int n_in,
                              void* d_out, int out_size, void* d_ws, size_t ws_size,
                              hipStream_t stream) {
  const float* x = (const float*)d_in[0];
  const int* ei = (const int*)d_in[1];
  const float* w = (const float*)d_in[2];
  const float* mask = (const float*)d_in[3];
  const int E = in_sizes[2];  // 131072
  int N = in_sizes[3];        // 2000
  const int* src = ei;
  const int* tgt = ei + E;
  float* out = (float*)d_out;

  const int Epad = E + PAD * N;

  size_t off = 0;
  auto alloc = [&](size_t bytes) -> void* {
    off = (off + 255) & ~(size_t)255;
    void* p = (char*)d_ws + off;
    off += bytes;
    return p;
  };
  uint32_t* edgeS = (uint32_t*)alloc((size_t)Epad * 4);  // contiguous with edgeT: one zero pass
  uint32_t* edgeT = (uint32_t*)alloc((size_t)Epad * 4);
  int* partS = (int*)alloc(8 * 2048 * 4);
  int* partT = (int*)alloc(8 * 2048 * 4);
  int* offS = (int*)alloc(2048 * 4);
  int* offT = (int*)alloc(2048 * 4);
  int* curS = (int*)alloc(2048 * 4);
  int* curT = (int*)alloc(2048 * 4);
  int* degS = (int*)alloc(2048 * 4);
  int* degT = (int*)alloc(2048 * 4);
  uint32_t* fx32 = (uint32_t*)alloc((size_t)2 * N * 64 * 4);  // parity double buffer
  uint32_t* err32 = (uint32_t*)alloc((size_t)N * 64 * 4);
  uint32_t* fxtag = (uint32_t*)alloc(2048 * 4);
  uint32_t* errtag = (uint32_t*)alloc(2048 * 4);

  hist_zero_kernel<<<32, 1024, 0, stream>>>(src, tgt, partS, partT, edgeS, E, N, 2 * Epad);
  scan_pad_kernel<<<2, 256, 0, stream>>>(partS, partT, offS, offT, curS, curT, degS, degT,
                                         fxtag, errtag, N);
  scatter_kernel<<<(E + 255) / 256, 256, 0, stream>>>(src, tgt, w, curS, curT, edgeS, edgeT, E);

  void* args[] = {(void*)&x,     (void*)&out,   (void*)&offS,  (void*)&degS, (void*)&edgeS,
                  (void*)&offT,  (void*)&degT,  (void*)&edgeT, (void*)&fx32, (void*)&err32,
                  (void*)&fxtag, (void*)&errtag, (void*)&mask, (void*)&N};
  hipLaunchCooperativeKernel((const void*)pc_main, dim3(NBLK), dim3(MAIN_T), args, 0, stream);
}

// Round 8
// 200.828 us; speedup vs baseline: 4.7640x; 2.1397x over previous
//
#include <hip/hip_runtime.h>

#define NITER 10
#define PAD 8        // CSR segment padding / accumulator depth
#define NBLK 250     // main-kernel blocks (250 * 8 node-pairs = 2000 nodes)
#define MAIN_T 1024  // 16 waves per block = 8 node-pairs (2 waves per node)
#define CAP_H 96     // per-wave LDS capacity for a HALF edge slice (max ~56)

// ---------------- helpers ----------------

__device__ __forceinline__ float bf2f_lo(uint32_t v) { return __uint_as_float(v << 16); }
__device__ __forceinline__ float bf2f_hi(uint32_t v) { return __uint_as_float(v & 0xFFFF0000u); }

__device__ __forceinline__ uint32_t f2bf_bits(float f) {  // RNE, top 16 bits
  uint32_t b = __float_as_uint(f);
  b += 0x7FFFu + ((b >> 16) & 1u);
  return b >> 16;
}
__device__ __forceinline__ uint32_t pack_bf16x2(float lo, float hi) {
  return f2bf_bits(lo) | (f2bf_bits(hi) << 16);
}

// ---------------- setup kernel 1: partial histograms + edge-array zeroing ----------------

__global__ __launch_bounds__(1024) void hist_zero_kernel(
    const int* __restrict__ src, const int* __restrict__ tgt,
    int* __restrict__ partS, int* __restrict__ partT,
    uint32_t* __restrict__ edges, int E, int N, int zwords) {
  if (blockIdx.x < 8) {
    __shared__ int h[4096];
    for (int i = threadIdx.x; i < 2 * N; i += 1024) h[i] = 0;
    __syncthreads();
    const int chunk = E / 8;
    const int base = blockIdx.x * chunk;
    for (int k = threadIdx.x; k < chunk; k += 1024) {
      int e = base + k;
      atomicAdd(&h[src[e]], 1);
      atomicAdd(&h[N + tgt[e]], 1);
    }
    __syncthreads();
    for (int i = threadIdx.x; i < N; i += 1024) {
      partS[blockIdx.x * 2048 + i] = h[i];
      partT[blockIdx.x * 2048 + i] = h[N + i];
    }
  } else {
    int tid = (blockIdx.x - 8) * 1024 + threadIdx.x;
    for (int i = tid; i < zwords; i += 24 * 1024) edges[i] = 0u;
  }
}

// ---------------- setup kernel 2: padded exclusive scan (+ zero barrier state) ----------

__global__ void scan_pad_kernel(const int* __restrict__ partS, const int* __restrict__ partT,
                                int* __restrict__ offS, int* __restrict__ offT,
                                int* __restrict__ curS, int* __restrict__ curT,
                                uint32_t* __restrict__ bar, int N) {
  if (blockIdx.x == 0 && threadIdx.x < 192) bar[threadIdx.x] = 0u;  // barrier ctrs + gen
  const int* part = (blockIdx.x == 0) ? partS : partT;
  int* off = (blockIdx.x == 0) ? offS : offT;
  int* cur = (blockIdx.x == 0) ? curS : curT;
  __shared__ int tsum[256];
  int tid = threadIdx.x;
  int base = tid * 8;
  int v[8];
  int s = 0;
#pragma unroll
  for (int i = 0; i < 8; ++i) {
    int idx = base + i;
    int c = 0;
    if (idx < N) {
#pragma unroll
      for (int k = 0; k < 8; ++k) c += part[k * 2048 + idx];
      c = (c + (PAD - 1)) & ~(PAD - 1);
    }
    v[i] = s;
    s += c;
  }
  tsum[tid] = s;
  __syncthreads();
  for (int d = 1; d < 256; d <<= 1) {
    int t = (tid >= d) ? tsum[tid - d] : 0;
    __syncthreads();
    tsum[tid] += t;
    __syncthreads();
  }
  int tbase = tsum[tid] - s;
#pragma unroll
  for (int i = 0; i < 8; ++i) {
    int idx = base + i;
    if (idx < N) {
      int o = tbase + v[i];
      off[idx] = o;
      cur[idx] = o;
    } else if (idx == N) {
      off[idx] = tbase + v[i];
    }
  }
}

// ---------------- setup kernel 3: scatter edges into CSR ----------------

__global__ void scatter_kernel(const int* __restrict__ src, const int* __restrict__ tgt,
                               const float* __restrict__ w,
                               int* __restrict__ curS, int* __restrict__ curT,
                               uint32_t* __restrict__ edgeS, uint32_t* __restrict__ edgeT, int E) {
  int e = blockIdx.x * blockDim.x + threadIdx.x;
  if (e < E) {
    int s = src[e], t = tgt[e];
    uint32_t wb = __float_as_uint(w[e]);
    wb = (wb + 0x7FFFu + ((wb >> 16) & 1u)) & 0xFFFF0000u;
    int p = atomicAdd(&curS[s], 1);
    edgeS[p] = (uint32_t)t | wb;  // mu pass: grouped by src, gathers fx[tgt]
    int q = atomicAdd(&curT[t], 1);
    edgeT[q] = (uint32_t)s | wb;  // agg pass: grouped by tgt, gathers err[src]
  }
}

// ---------------- main cooperative kernel ----------------
// 2 waves per node: wave (n, half). Each gathers HALF the node's edge list
// (chain length halved), partials combined via LDS; primary (half==0) owns all
// node state (x, fx, err) and publishes. Tree barrier as in round 4 (proven):
// vmcnt(0) drains sc1 write-through stores to LLC before arrival; all message
// reads are sc1 (LLC) loads -> no cache invalidation anywhere.

__device__ __forceinline__ void gbar(uint32_t* bar, uint32_t target) {
  asm volatile("s_waitcnt vmcnt(0)" ::: "memory");
  __syncthreads();
  if (threadIdx.x == 0) {
    uint32_t* leaf = bar + (blockIdx.x & 7) * 16;
    uint32_t* root = bar + 128;
    uint32_t* gen = bar + 144;
    const uint32_t leafsz = ((blockIdx.x & 7) < 2) ? 32u : 31u;  // 250 = 2*32 + 6*31
    uint32_t lo = __hip_atomic_fetch_add(leaf, 1u, __ATOMIC_RELAXED, __HIP_MEMORY_SCOPE_AGENT);
    if (lo == leafsz - 1) {
      __hip_atomic_store(leaf, 0u, __ATOMIC_RELAXED, __HIP_MEMORY_SCOPE_AGENT);
      uint32_t ro = __hip_atomic_fetch_add(root, 1u, __ATOMIC_RELAXED, __HIP_MEMORY_SCOPE_AGENT);
      if (ro == 7u) {
        __hip_atomic_store(root, 0u, __ATOMIC_RELAXED, __HIP_MEMORY_SCOPE_AGENT);
        __hip_atomic_store(gen, target, __ATOMIC_RELAXED, __HIP_MEMORY_SCOPE_AGENT);
      }
    }
    while (__hip_atomic_load(gen, __ATOMIC_RELAXED, __HIP_MEMORY_SCOPE_AGENT) < target)
      __builtin_amdgcn_s_sleep(1);
  }
  __syncthreads();
  asm volatile("" ::: "memory");  // compiler fence only
}

__device__ __forceinline__ void gather_lds(const uint32_t* __restrict__ se, int len,
                                           const uint32_t* buf, int lane,
                                           float& o0, float& o1) {
  float a0[PAD], a1[PAD];
#pragma unroll
  for (int j = 0; j < PAD; ++j) { a0[j] = 0.f; a1[j] = 0.f; }
#pragma unroll 2
  for (int p = 0; p < len; p += PAD) {
    uint32_t e[PAD];
#pragma unroll
    for (int j = 0; j < PAD; ++j) e[j] = se[p + j];
    uint32_t v[PAD];
#pragma unroll
    for (int j = 0; j < PAD; ++j)
      v[j] = __hip_atomic_load(&buf[((e[j] & 0xFFFFu) << 6) + lane], __ATOMIC_RELAXED,
                               __HIP_MEMORY_SCOPE_AGENT);
#pragma unroll
    for (int j = 0; j < PAD; ++j) {
      float wj = __uint_as_float(e[j] & 0xFFFF0000u);
      a0[j] = fmaf(wj, bf2f_lo(v[j]), a0[j]);
      a1[j] = fmaf(wj, bf2f_hi(v[j]), a1[j]);
    }
  }
  o0 = ((a0[0] + a0[1]) + (a0[2] + a0[3])) + ((a0[4] + a0[5]) + (a0[6] + a0[7]));
  o1 = ((a1[0] + a1[1]) + (a1[2] + a1[3])) + ((a1[4] + a1[5]) + (a1[6] + a1[7]));
}

__device__ __forceinline__ void gather_glb(const uint32_t* __restrict__ ed, int len,
                                           const uint32_t* buf, int lane,
                                           float& o0, float& o1) {
  float a0[PAD], a1[PAD];
#pragma unroll
  for (int j = 0; j < PAD; ++j) { a0[j] = 0.f; a1[j] = 0.f; }
#pragma unroll 2
  for (int p = 0; p < len; p += PAD) {
    uint32_t e[PAD];
#pragma unroll
    for (int j = 0; j < PAD; ++j) e[j] = ed[p + j];
    uint32_t v[PAD];
#pragma unroll
    for (int j = 0; j < PAD; ++j)
      v[j] = __hip_atomic_load(&buf[((e[j] & 0xFFFFu) << 6) + lane], __ATOMIC_RELAXED,
                               __HIP_MEMORY_SCOPE_AGENT);
#pragma unroll
    for (int j = 0; j < PAD; ++j) {
      float wj = __uint_as_float(e[j] & 0xFFFF0000u);
      a0[j] = fmaf(wj, bf2f_lo(v[j]), a0[j]);
      a1[j] = fmaf(wj, bf2f_hi(v[j]), a1[j]);
    }
  }
  o0 = ((a0[0] + a0[1]) + (a0[2] + a0[3])) + ((a0[4] + a0[5]) + (a0[6] + a0[7]));
  o1 = ((a1[0] + a1[1]) + (a1[2] + a1[3])) + ((a1[4] + a1[5]) + (a1[6] + a1[7]));
}

__device__ __forceinline__ void publish(uint32_t* p, uint32_t val) {
  __hip_atomic_store(p, val, __ATOMIC_RELAXED, __HIP_MEMORY_SCOPE_AGENT);
}

__global__ __launch_bounds__(MAIN_T, 4) void pc_main(
    const float* __restrict__ x, float* __restrict__ out,
    const int* __restrict__ offS, const uint32_t* __restrict__ edS,
    const int* __restrict__ offT, const uint32_t* __restrict__ edT,
    uint32_t* fx32, uint32_t* err32, const float* __restrict__ mask,
    uint32_t* bar, int N) {
  const int wid = threadIdx.x >> 6;
  const int lane = threadIdx.x & 63;
  const int pair = wid >> 1;   // 0..7: node slot in block
  const int half = wid & 1;    // 0 = primary (owns state), 1 = secondary
  const int n = blockIdx.x * 8 + pair;  // 250*8 = 2000, always valid
  const int i = (n << 6) + lane;

  const int s0 = offS[n], lenS = offS[n + 1] - s0;
  const int t0 = offT[n], lenT = offT[n + 1] - t0;
  // split each (padded) edge list between the wave pair at a PAD boundary
  const int midS = min(((lenS >> 1) + (PAD - 1)) & ~(PAD - 1), lenS);
  const int midT = min(((lenT >> 1) + (PAD - 1)) & ~(PAD - 1), lenT);
  const int aS = half ? midS : 0, hlenS = (half ? lenS : midS) - aS;
  const int aT = half ? midT : 0, hlenT = (half ? lenT : midT) - aT;

  // stage this wave's half-slices into LDS once (wave-private)
  __shared__ uint32_t sE[2][MAIN_T / 64][CAP_H];
  __shared__ float2 psum[MAIN_T / 128][64];
  const bool fS = (hlenS <= CAP_H), fT = (hlenT <= CAP_H);
  if (fS)
    for (int k = lane; k < hlenS; k += 64) sE[0][wid][k] = edS[s0 + aS + k];
  if (fT)
    for (int k = lane; k < hlenT; k += 64) sE[1][wid][k] = edT[t0 + aT + k];

  // primary owns node state; lane l owns batch (2l, 2l+1)
  float m = 0.f, x0 = 0.f, x1 = 0.f, fx0 = 0.f, fx1 = 0.f, e0 = 0.f, e1 = 0.f;
  if (half == 0) {
    m = mask[n];
    x0 = x[(2 * lane) * N + n];
    x1 = x[(2 * lane + 1) * N + n];
    fx0 = tanhf(x0);
    fx1 = tanhf(x1);
    publish(&fx32[i], pack_bf16x2(fx0, fx1));
  }
  uint32_t gen = 0;
  gbar(bar, ++gen);

  for (int it = 0; it < NITER; ++it) {
    // ---- phase 1: mu partial-gather over fx, combine, publish err ----
    float p0, p1;
    if (fS) gather_lds(&sE[0][wid][0], hlenS, fx32, lane, p0, p1);
    else    gather_glb(edS + s0 + aS, hlenS, fx32, lane, p0, p1);
    if (half) psum[pair][lane] = make_float2(p0, p1);
    __syncthreads();
    if (half == 0) {
      float2 q = psum[pair][lane];
      e0 = (x0 - (p0 + q.x)) * m;
      e1 = (x1 - (p1 + q.y)) * m;
      publish(&err32[i], pack_bf16x2(e0, e1));
    }
    gbar(bar, ++gen);

    // ---- phase 2: agg partial-gather over err, combine, update x, publish fx ----
    if (fT) gather_lds(&sE[1][wid][0], hlenT, err32, lane, p0, p1);
    else    gather_glb(edT + t0 + aT, hlenT, err32, lane, p0, p1);
    if (half) psum[pair][lane] = make_float2(p0, p1);
    __syncthreads();
    if (half == 0) {
      float2 q = psum[pair][lane];
      const float dx0 = e0 - (1.f - fx0 * fx0) * (p0 + q.x);
      const float dx1 = e1 - (1.f - fx1 * fx1) * (p1 + q.y);
      x0 -= 0.5f * dx0 * m;
      x1 -= 0.5f * dx1 * m;
      fx0 = tanhf(x0);
      fx1 = tanhf(x1);
      if (it < NITER - 1) publish(&fx32[i], pack_bf16x2(fx0, fx1));
    }
    if (it < NITER - 1) gbar(bar, ++gen);
  }
  if (half == 0) {
    out[(2 * lane) * N + n] = x0;
    out[(2 * lane + 1) * N + n] = x1;
  }
}

// ---------------- host ----------------

extern "C" void kernel_launch(void* const* d_in, const int* in_sizes, int n_in,
                              void* d_out, int out_size, void* d_ws, size_t ws_size,
                              hipStream_t stream) {
  const float* x = (const float*)d_in[0];
  const int* ei = (const int*)d_in[1];
  const float* w = (const float*)d_in[2];
  const float* mask = (const float*)d_in[3];
  const int E = in_sizes[2];  // 131072
  int N = in_sizes[3];        // 2000
  const int* src = ei;
  const int* tgt = ei + E;
  float* out = (float*)d_out;

  const int Epad = E + PAD * N;

  size_t off = 0;
  auto alloc = [&](size_t bytes) -> void* {
    off = (off + 255) & ~(size_t)255;
    void* p = (char*)d_ws + off;
    off += bytes;
    return p;
  };
  uint32_t* edgeS = (uint32_t*)alloc((size_t)Epad * 4);  // contiguous with edgeT: one zero pass
  uint32_t* edgeT = (uint32_t*)alloc((size_t)Epad * 4);
  int* partS = (int*)alloc(8 * 2048 * 4);
  int* partT = (int*)alloc(8 * 2048 * 4);
  int* offS = (int*)alloc(2048 * 4);
  int* offT = (int*)alloc(2048 * 4);
  int* curS = (int*)alloc(2048 * 4);
  int* curT = (int*)alloc(2048 * 4);
  uint32_t* fx32 = (uint32_t*)alloc((size_t)N * 64 * 4);
  uint32_t* err32 = (uint32_t*)alloc((size_t)N * 64 * 4);
  uint32_t* bar = (uint32_t*)alloc(256 * 4);

  hist_zero_kernel<<<32, 1024, 0, stream>>>(src, tgt, partS, partT, edgeS, E, N, 2 * Epad);
  scan_pad_kernel<<<2, 256, 0, stream>>>(partS, partT, offS, offT, curS, curT, bar, N);
  scatter_kernel<<<(E + 255) / 256, 256, 0, stream>>>(src, tgt, w, curS, curT, edgeS, edgeT, E);

  void* args[] = {(void*)&x,    (void*)&out,   (void*)&offS, (void*)&edgeS,
                  (void*)&offT, (void*)&edgeT, (void*)&fx32, (void*)&err32,
                  (void*)&mask, (void*)&bar,   (void*)&N};
  hipLaunchCooperativeKernel((const void*)pc_main, dim3(NBLK), dim3(MAIN_T), args, 0, stream);
}